// Round 7
// baseline (483.047 us; speedup 1.0000x reference)
//
#include <hip/hip_runtime.h>

#define NUM_CARDS 50000
#define NM1 49999
#define BATCH 1024
#define BPAD 50176            // padded cards: multiple of 448; B rows NM1..BPAD-1 are zero
#define NPAD (BPAD - NM1)     // 177 pad cards, each adds exp(0)=1 to S1
#define CARDS_PER_BLOCK 448   // 7 full slabs of 64 -- no tail code
#define NSLAB 7
#define GRIDX 16              // 16 row-groups of 64 rows
#define GRIDY (BPAD / CARDS_PER_BLOCK)   // 112 -> grid = 1792 blocks = 7/CU exactly
#define KLEPS 1e-7f
#define PREP_BBLOCKS (BPAD / 16)         // 3136: 16 cards per block (4 waves x 4 cards)

typedef __attribute__((ext_vector_type(8))) short short8;   // 8 bf16
typedef __attribute__((ext_vector_type(4))) float f32x4;
typedef float f32x4u __attribute__((ext_vector_type(4), aligned(4)));  // adj rows only 4B-aligned
typedef __attribute__((ext_vector_type(4))) unsigned short ushort4v;

// ws layout:
//   A bf16 : [0, 131072)        1024*64*2
//   B bf16 : [131072, 6553600)  50176*64*2, row j = l2norm(card j+1), pads zero
//   S1..S4 : [6553600, 6569984) 4 x 1024 f32
#define A_OFF  0
#define B_OFF  131072
#define S_OFF  6553600

__device__ inline unsigned short f2bf(float x) {
    unsigned int u = __float_as_uint(x);
    return (unsigned short)((u + 0x7FFFu + ((u >> 16) & 1u)) >> 16);  // RNE
}

// ---- prep: blocks [0,3136) normalize B (float4, 4 cards/wave); [3136,3264) MLP; 3136 zeroes S ----
__global__ __launch_bounds__(256) void prep_kernel(
    const int* __restrict__ idx, const float* __restrict__ ce,
    const float* __restrict__ W1, const float* __restrict__ b1,
    const float* __restrict__ W2, const float* __restrict__ b2,
    unsigned short* __restrict__ Abf, unsigned short* __restrict__ Bbf,
    float* __restrict__ S)
{
    const int bid  = blockIdx.x;
    const int t    = threadIdx.x;
    const int lane = t & 63;
    const int wv   = t >> 6;

    if (bid < PREP_BBLOCKS) {
        // wave handles 4 cards; 16 lanes per card, float4 per lane
        const int j = bid * 16 + wv * 4 + (lane >> 4);   // B row (card j+1), j < BPAD
        const int e = (lane & 15) * 4;
        f32x4 v = {0.f, 0.f, 0.f, 0.f};
        if (j < NM1) v = *(const f32x4*)(ce + (size_t)(j + 1) * 64 + e);
        float ss = v.x * v.x + v.y * v.y + v.z * v.z + v.w * v.w;
        #pragma unroll
        for (int s = 1; s <= 8; s <<= 1) ss += __shfl_xor(ss, s, 64);
        const float inv = rsqrtf(fmaxf(ss, 1e-12f));
        ushort4v o;
        o.x = f2bf(v.x * inv); o.y = f2bf(v.y * inv);
        o.z = f2bf(v.z * inv); o.w = f2bf(v.w * inv);
        *(ushort4v*)(Bbf + (size_t)j * 64 + e) = o;
        return;
    }

    if (bid == PREP_BBLOCKS) {
        for (int k = t; k < 4096; k += 256) S[k] = 0.f;
    }

    __shared__ float emb_s[8][64];
    __shared__ float hs[8][256];
    __shared__ int idx_s[8];
    const int i0 = (bid - PREP_BBLOCKS) * 8;
    if (t < 8) idx_s[t] = idx[i0 + t];
    __syncthreads();
    for (int e = t; e < 8 * 64; e += 256) {
        int g = e >> 6, k = e & 63;
        emb_s[g][k] = ce[idx_s[g] * 64 + k];
    }
    __syncthreads();
    {   // hidden layer
        const int j = t;
        float a8[8];
        float bj = b1[j];
        #pragma unroll
        for (int g = 0; g < 8; ++g) a8[g] = bj;
        for (int k = 0; k < 64; ++k) {
            float w = W1[k * 256 + j];
            #pragma unroll
            for (int g = 0; g < 8; ++g) a8[g] = fmaf(emb_s[g][k], w, a8[g]);
        }
        #pragma unroll
        for (int g = 0; g < 8; ++g) hs[g][j] = fmaxf(a8[g], 0.f);
    }
    __syncthreads();
    {   // output layer + l2norm -> bf16
        const int d = lane;
        float o0 = b2[d], o1 = b2[d];
        for (int j = 0; j < 256; ++j) {
            float w2 = W2[j * 64 + d];
            o0 = fmaf(hs[wv][j],     w2, o0);
            o1 = fmaf(hs[wv + 4][j], w2, o1);
        }
        float s0 = o0 * o0, s1 = o1 * o1;
        #pragma unroll
        for (int s = 1; s <= 32; s <<= 1) {
            s0 += __shfl_xor(s0, s, 64);
            s1 += __shfl_xor(s1, s, 64);
        }
        o0 *= rsqrtf(fmaxf(s0, 1e-12f));
        o1 *= rsqrtf(fmaxf(s1, 1e-12f));
        Abf[(i0 + wv) * 64 + d]     = f2bf(o0);
        Abf[(i0 + wv + 4) * 64 + d] = f2bf(o1);
    }
}

// ---- fused streaming sweep, operand-swapped MFMA: score layout == adj float4 layout ----
// mfma(card_frag, batch_frag): lane(m,quad) reg r holds s(row r0+m, card cb+16g+quad*4+r),
// == the f32x4 adj load at rowp(m)+cb+16g+4*quad. No LDS, no realign.
// Grid 16x112 = 1792 blocks = 7/CU: 28 waves/CU (vs 16 at the old 4/CU) for
// latency hiding -- round-4/6 counters showed latency-bound (Occ 32%, VALU 12%).
// No device fence here (round-4 A/B: threadfence storm collapsed streaming BW).
__global__ __launch_bounds__(256, 7) void fused_kernel(
    const unsigned short* __restrict__ Abf,
    const unsigned short* __restrict__ Bbf,
    const float* __restrict__ adj,
    const float* __restrict__ temp_p,
    float* __restrict__ S)
{
    const int lane = threadIdx.x & 63;
    const int wv   = threadIdx.x >> 6;
    const int m    = lane & 15;
    const int quad = lane >> 4;
    const int row  = blockIdx.x * 64 + wv * 16 + m;   // this lane's batch row
    const float T  = *temp_p;

    // batch fragment (second MFMA operand): row, dims quad*8..+7 / 32+quad*8..+7
    const size_t arow = (size_t)row * 64;
    const short8 a0 = *(const short8*)(Abf + arow + quad * 8);
    const short8 a1 = *(const short8*)(Abf + arow + 32 + quad * 8);

    const float* __restrict__ rowp = adj + (size_t)row * NM1;
    const int ysub = 4 * quad;     // element offset within each 16-card group

    float rs1 = 0.f, rs2 = 0.f, rs3 = 0.f, rs4 = 0.f;
    const int cbase0 = blockIdx.y * CARDS_PER_BLOCK;

    // 1-slab-ahead adj prefetch (raw values; invalid cards = 0 exactly)
    f32x4 yn[4];
    {
        const int cb = cbase0;
        if (cb + 63 < NM1) {
            #pragma unroll
            for (int g = 0; g < 4; ++g)
                yn[g] = *(const f32x4u*)(rowp + cb + 16 * g + ysub);
        } else {
            #pragma unroll
            for (int g = 0; g < 4; ++g) {
                #pragma unroll
                for (int k = 0; k < 4; ++k) {
                    const int c = cb + 16 * g + ysub + k;
                    yn[g][k] = (c < NM1) ? rowp[c] : 0.f;
                }
            }
        }
    }

    for (int slab = 0; slab < NSLAB; ++slab) {
        const int cb = cbase0 + slab * 64;

        f32x4 y[4];
        #pragma unroll
        for (int g = 0; g < 4; ++g) y[g] = yn[g];

        if (slab + 1 < NSLAB) {     // issue next slab's adj loads now
            const int nb = cb + 64;
            if (nb + 63 < NM1) {
                #pragma unroll
                for (int g = 0; g < 4; ++g)
                    yn[g] = *(const f32x4u*)(rowp + nb + 16 * g + ysub);
            } else {
                #pragma unroll
                for (int g = 0; g < 4; ++g) {
                    #pragma unroll
                    for (int k = 0; k < 4; ++k) {
                        const int c = nb + 16 * g + ysub + k;
                        yn[g][k] = (c < NM1) ? rowp[c] : 0.f;
                    }
                }
            }
        }

        // card fragments (first MFMA operand): card cb+16g+m, dims quad*8..
        short8 c0[4], c1[4];
        #pragma unroll
        for (int g = 0; g < 4; ++g) {
            const unsigned short* bp = Bbf + (size_t)(cb + 16 * g + m) * 64;
            c0[g] = *(const short8*)(bp + quad * 8);
            c1[g] = *(const short8*)(bp + 32 + quad * 8);
        }

        const bool full = (cb + 63 < NM1);
        #pragma unroll
        for (int g = 0; g < 4; ++g) {
            f32x4 z = {0.f, 0.f, 0.f, 0.f};
            f32x4 d = __builtin_amdgcn_mfma_f32_16x16x32_bf16(
                          c1[g], a1,
                          __builtin_amdgcn_mfma_f32_16x16x32_bf16(c0[g], a0, z, 0, 0, 0),
                          0, 0, 0);
            if (full) {
                #pragma unroll
                for (int k = 0; k < 4; ++k) {
                    const float s = d[k];
                    rs1 += __expf(T * s);
                    const float tv = fmaxf(y[g][k], KLEPS);
                    rs3 += tv * __logf(tv);
                    rs4 += tv;
                    rs2 += tv * s;
                }
            } else {
                #pragma unroll
                for (int k = 0; k < 4; ++k) {
                    const float s = d[k];
                    rs1 += __expf(T * s);   // pad cards score 0 -> exp(0)=1, removed in fin
                    const int c = cb + 16 * g + ysub + k;
                    if (c < NM1) {
                        const float tv = fmaxf(y[g][k], KLEPS);
                        rs3 += tv * __logf(tv);
                        rs4 += tv;
                        rs2 += tv * s;
                    }
                }
            }
        }
    }

    // quads hold disjoint card subsets of the same row: reduce over lane bits 4-5
    rs1 += __shfl_xor(rs1, 16, 64); rs1 += __shfl_xor(rs1, 32, 64);
    rs2 += __shfl_xor(rs2, 16, 64); rs2 += __shfl_xor(rs2, 32, 64);
    rs3 += __shfl_xor(rs3, 16, 64); rs3 += __shfl_xor(rs3, 32, 64);
    rs4 += __shfl_xor(rs4, 16, 64); rs4 += __shfl_xor(rs4, 32, 64);

    // one atomic per lane: quad q writes sum q for this row
    const float vq = (quad == 0) ? rs1 : (quad == 1) ? rs2 : (quad == 2) ? rs3 : rs4;
    atomicAdd(&S[quad * 1024 + row], vq);
}

// ---- finalize: loss = sum_r [S3 - T*S2 + log(S1-NPAD)*S4] / (B ln2) + T^2/100 ----
__global__ __launch_bounds__(256) void fin_kernel(
    const float* __restrict__ S, const float* __restrict__ temp_p,
    float* __restrict__ out)
{
    const float* S1 = S; const float* S2 = S + 1024;
    const float* S3 = S + 2048; const float* S4 = S + 3072;
    const float T = *temp_p;
    const int t = threadIdx.x;
    float local = 0.f;
    #pragma unroll
    for (int p = 0; p < 4; ++p) {
        const int row = t + p * 256;
        float lse = __logf(S1[row] - (float)NPAD);
        local += S3[row] - T * S2[row] + lse * S4[row];
    }
    #pragma unroll
    for (int s = 1; s <= 32; s <<= 1) local += __shfl_xor(local, s, 64);
    __shared__ float wacc[4];
    if ((t & 63) == 0) wacc[t >> 6] = local;
    __syncthreads();
    if (t == 0)
        out[0] = (wacc[0] + wacc[1] + wacc[2] + wacc[3])
                 * (1.0f / (BATCH * 0.69314718055994531f))
               + T * T * 0.01f;
}

extern "C" void kernel_launch(void* const* d_in, const int* in_sizes, int n_in,
                              void* d_out, int out_size, void* d_ws, size_t ws_size,
                              hipStream_t stream) {
    const int*   single_card = (const int*)d_in[0];
    const float* adj         = (const float*)d_in[1];
    const float* ce          = (const float*)d_in[2];
    const float* W1          = (const float*)d_in[3];
    const float* b1          = (const float*)d_in[4];
    const float* W2          = (const float*)d_in[5];
    const float* b2          = (const float*)d_in[6];
    const float* temp        = (const float*)d_in[7];

    char* ws = (char*)d_ws;
    unsigned short* Abf = (unsigned short*)(ws + A_OFF);
    unsigned short* Bbf = (unsigned short*)(ws + B_OFF);
    float* S            = (float*)(ws + S_OFF);

    prep_kernel<<<PREP_BBLOCKS + 128, 256, 0, stream>>>(single_card, ce, W1, b1, W2, b2,
                                                        Abf, Bbf, S);
    fused_kernel<<<dim3(GRIDX, GRIDY), 256, 0, stream>>>(Abf, Bbf, adj, temp, S);
    fin_kernel<<<1, 256, 0, stream>>>(S, temp, (float*)d_out);
}

// Round 9
// 345.733 us; speedup vs baseline: 1.3972x; 1.3972x over previous
//
#include <hip/hip_runtime.h>

#define NUM_CARDS 50000
#define NM1 49999
#define BATCH 1024
#define BPAD 50176            // padded cards: multiple of 448; B rows NM1..BPAD-1 are zero
#define NPAD (BPAD - NM1)     // 177 pad cards, each adds exp(0)=1 to S1
#define CARDS_PER_BLOCK 448   // 7 full slabs of 64 -- no tail code
#define NSLAB 7
#define GRIDX 16              // 16 row-groups of 64 rows
#define GRIDY (BPAD / CARDS_PER_BLOCK)   // 112 -> grid = 1792 blocks = 7/CU exactly
#define KLEPS 1e-7f
#define PREP_BBLOCKS (BPAD / 16)         // 3136: 16 cards per block (4 waves x 4 cards)

typedef __attribute__((ext_vector_type(8))) short short8;   // 8 bf16
typedef __attribute__((ext_vector_type(4))) float f32x4;
typedef float f32x4u __attribute__((ext_vector_type(4), aligned(4)));  // adj rows only 4B-aligned
typedef __attribute__((ext_vector_type(4))) unsigned short ushort4v;

// ws layout:
//   A bf16 : [0, 131072)        1024*64*2
//   B bf16 : [131072, 6553600)  50176*64*2, row j = l2norm(card j+1), pads zero
//   S1..S4 : [6553600, 6569984) 4 x 1024 f32
#define A_OFF  0
#define B_OFF  131072
#define S_OFF  6553600

__device__ inline unsigned short f2bf(float x) {
    unsigned int u = __float_as_uint(x);
    return (unsigned short)((u + 0x7FFFu + ((u >> 16) & 1u)) >> 16);  // RNE
}

// ---- prep: blocks [0,3136) normalize B (float4, 4 cards/wave); [3136,3264) MLP; 3136 zeroes S ----
__global__ __launch_bounds__(256) void prep_kernel(
    const int* __restrict__ idx, const float* __restrict__ ce,
    const float* __restrict__ W1, const float* __restrict__ b1,
    const float* __restrict__ W2, const float* __restrict__ b2,
    unsigned short* __restrict__ Abf, unsigned short* __restrict__ Bbf,
    float* __restrict__ S)
{
    const int bid  = blockIdx.x;
    const int t    = threadIdx.x;
    const int lane = t & 63;
    const int wv   = t >> 6;

    if (bid < PREP_BBLOCKS) {
        // wave handles 4 cards; 16 lanes per card, float4 per lane
        const int j = bid * 16 + wv * 4 + (lane >> 4);   // B row (card j+1), j < BPAD
        const int e = (lane & 15) * 4;
        f32x4 v = {0.f, 0.f, 0.f, 0.f};
        if (j < NM1) v = *(const f32x4*)(ce + (size_t)(j + 1) * 64 + e);
        float ss = v.x * v.x + v.y * v.y + v.z * v.z + v.w * v.w;
        #pragma unroll
        for (int s = 1; s <= 8; s <<= 1) ss += __shfl_xor(ss, s, 64);
        const float inv = rsqrtf(fmaxf(ss, 1e-12f));
        ushort4v o;
        o.x = f2bf(v.x * inv); o.y = f2bf(v.y * inv);
        o.z = f2bf(v.z * inv); o.w = f2bf(v.w * inv);
        *(ushort4v*)(Bbf + (size_t)j * 64 + e) = o;
        return;
    }

    if (bid == PREP_BBLOCKS) {
        for (int k = t; k < 4096; k += 256) S[k] = 0.f;
    }

    __shared__ float emb_s[8][64];
    __shared__ float hs[8][256];
    __shared__ int idx_s[8];
    const int i0 = (bid - PREP_BBLOCKS) * 8;
    if (t < 8) idx_s[t] = idx[i0 + t];
    __syncthreads();
    for (int e = t; e < 8 * 64; e += 256) {
        int g = e >> 6, k = e & 63;
        emb_s[g][k] = ce[idx_s[g] * 64 + k];
    }
    __syncthreads();
    {   // hidden layer
        const int j = t;
        float a8[8];
        float bj = b1[j];
        #pragma unroll
        for (int g = 0; g < 8; ++g) a8[g] = bj;
        for (int k = 0; k < 64; ++k) {
            float w = W1[k * 256 + j];
            #pragma unroll
            for (int g = 0; g < 8; ++g) a8[g] = fmaf(emb_s[g][k], w, a8[g]);
        }
        #pragma unroll
        for (int g = 0; g < 8; ++g) hs[g][j] = fmaxf(a8[g], 0.f);
    }
    __syncthreads();
    {   // output layer + l2norm -> bf16
        const int d = lane;
        float o0 = b2[d], o1 = b2[d];
        for (int j = 0; j < 256; ++j) {
            float w2 = W2[j * 64 + d];
            o0 = fmaf(hs[wv][j],     w2, o0);
            o1 = fmaf(hs[wv + 4][j], w2, o1);
        }
        float s0 = o0 * o0, s1 = o1 * o1;
        #pragma unroll
        for (int s = 1; s <= 32; s <<= 1) {
            s0 += __shfl_xor(s0, s, 64);
            s1 += __shfl_xor(s1, s, 64);
        }
        o0 *= rsqrtf(fmaxf(s0, 1e-12f));
        o1 *= rsqrtf(fmaxf(s1, 1e-12f));
        Abf[(i0 + wv) * 64 + d]     = f2bf(o0);
        Abf[(i0 + wv + 4) * 64 + d] = f2bf(o1);
    }
}

// ---- fused streaming sweep, operand-swapped MFMA: score layout == adj float4 layout ----
// mfma(card_frag, batch_frag): lane(m,quad) reg r holds s(row r0+m, card cb+16g+quad*4+r),
// == the f32x4 adj load at rowp(m)+cb+16g+4*quad. No LDS, no realign.
// Grid 16x112 = 1792 blocks = 7/CU; residency comes from the compiler's natural
// ~52-VGPR allocation (512/52 -> 8 waves/EU possible), NOT from launch_bounds.
// Round-7 lesson: __launch_bounds__(256,7) squeezed the allocator (VGPR 36) and
// spilled ~560 MB of scratch traffic per dispatch (WRITE_SIZE 1MB->371MB). Keep (256,4).
__global__ __launch_bounds__(256, 4) void fused_kernel(
    const unsigned short* __restrict__ Abf,
    const unsigned short* __restrict__ Bbf,
    const float* __restrict__ adj,
    const float* __restrict__ temp_p,
    float* __restrict__ S)
{
    const int lane = threadIdx.x & 63;
    const int wv   = threadIdx.x >> 6;
    const int m    = lane & 15;
    const int quad = lane >> 4;
    const int row  = blockIdx.x * 64 + wv * 16 + m;   // this lane's batch row
    const float T  = *temp_p;

    // batch fragment (second MFMA operand): row, dims quad*8..+7 / 32+quad*8..+7
    const size_t arow = (size_t)row * 64;
    const short8 a0 = *(const short8*)(Abf + arow + quad * 8);
    const short8 a1 = *(const short8*)(Abf + arow + 32 + quad * 8);

    const float* __restrict__ rowp = adj + (size_t)row * NM1;
    const int ysub = 4 * quad;     // element offset within each 16-card group

    float rs1 = 0.f, rs2 = 0.f, rs3 = 0.f, rs4 = 0.f;
    const int cbase0 = blockIdx.y * CARDS_PER_BLOCK;

    // 1-slab-ahead adj prefetch (raw values; invalid cards = 0 exactly)
    f32x4 yn[4];
    {
        const int cb = cbase0;
        if (cb + 63 < NM1) {
            #pragma unroll
            for (int g = 0; g < 4; ++g)
                yn[g] = *(const f32x4u*)(rowp + cb + 16 * g + ysub);
        } else {
            #pragma unroll
            for (int g = 0; g < 4; ++g) {
                #pragma unroll
                for (int k = 0; k < 4; ++k) {
                    const int c = cb + 16 * g + ysub + k;
                    yn[g][k] = (c < NM1) ? rowp[c] : 0.f;
                }
            }
        }
    }

    for (int slab = 0; slab < NSLAB; ++slab) {
        const int cb = cbase0 + slab * 64;

        f32x4 y[4];
        #pragma unroll
        for (int g = 0; g < 4; ++g) y[g] = yn[g];

        if (slab + 1 < NSLAB) {     // issue next slab's adj loads now
            const int nb = cb + 64;
            if (nb + 63 < NM1) {
                #pragma unroll
                for (int g = 0; g < 4; ++g)
                    yn[g] = *(const f32x4u*)(rowp + nb + 16 * g + ysub);
            } else {
                #pragma unroll
                for (int g = 0; g < 4; ++g) {
                    #pragma unroll
                    for (int k = 0; k < 4; ++k) {
                        const int c = nb + 16 * g + ysub + k;
                        yn[g][k] = (c < NM1) ? rowp[c] : 0.f;
                    }
                }
            }
        }

        // card fragments (first MFMA operand): card cb+16g+m, dims quad*8..
        short8 c0[4], c1[4];
        #pragma unroll
        for (int g = 0; g < 4; ++g) {
            const unsigned short* bp = Bbf + (size_t)(cb + 16 * g + m) * 64;
            c0[g] = *(const short8*)(bp + quad * 8);
            c1[g] = *(const short8*)(bp + 32 + quad * 8);
        }

        const bool full = (cb + 63 < NM1);
        #pragma unroll
        for (int g = 0; g < 4; ++g) {
            f32x4 z = {0.f, 0.f, 0.f, 0.f};
            f32x4 d = __builtin_amdgcn_mfma_f32_16x16x32_bf16(
                          c1[g], a1,
                          __builtin_amdgcn_mfma_f32_16x16x32_bf16(c0[g], a0, z, 0, 0, 0),
                          0, 0, 0);
            if (full) {
                #pragma unroll
                for (int k = 0; k < 4; ++k) {
                    const float s = d[k];
                    rs1 += __expf(T * s);
                    const float tv = fmaxf(y[g][k], KLEPS);
                    rs3 += tv * __logf(tv);
                    rs4 += tv;
                    rs2 += tv * s;
                }
            } else {
                #pragma unroll
                for (int k = 0; k < 4; ++k) {
                    const float s = d[k];
                    rs1 += __expf(T * s);   // pad cards score 0 -> exp(0)=1, removed in fin
                    const int c = cb + 16 * g + ysub + k;
                    if (c < NM1) {
                        const float tv = fmaxf(y[g][k], KLEPS);
                        rs3 += tv * __logf(tv);
                        rs4 += tv;
                        rs2 += tv * s;
                    }
                }
            }
        }
    }

    // quads hold disjoint card subsets of the same row: reduce over lane bits 4-5
    rs1 += __shfl_xor(rs1, 16, 64); rs1 += __shfl_xor(rs1, 32, 64);
    rs2 += __shfl_xor(rs2, 16, 64); rs2 += __shfl_xor(rs2, 32, 64);
    rs3 += __shfl_xor(rs3, 16, 64); rs3 += __shfl_xor(rs3, 32, 64);
    rs4 += __shfl_xor(rs4, 16, 64); rs4 += __shfl_xor(rs4, 32, 64);

    // one atomic per lane: quad q writes sum q for this row
    const float vq = (quad == 0) ? rs1 : (quad == 1) ? rs2 : (quad == 2) ? rs3 : rs4;
    atomicAdd(&S[quad * 1024 + row], vq);
}

// ---- finalize: loss = sum_r [S3 - T*S2 + log(S1-NPAD)*S4] / (B ln2) + T^2/100 ----
__global__ __launch_bounds__(256) void fin_kernel(
    const float* __restrict__ S, const float* __restrict__ temp_p,
    float* __restrict__ out)
{
    const float* S1 = S; const float* S2 = S + 1024;
    const float* S3 = S + 2048; const float* S4 = S + 3072;
    const float T = *temp_p;
    const int t = threadIdx.x;
    float local = 0.f;
    #pragma unroll
    for (int p = 0; p < 4; ++p) {
        const int row = t + p * 256;
        float lse = __logf(S1[row] - (float)NPAD);
        local += S3[row] - T * S2[row] + lse * S4[row];
    }
    #pragma unroll
    for (int s = 1; s <= 32; s <<= 1) local += __shfl_xor(local, s, 64);
    __shared__ float wacc[4];
    if ((t & 63) == 0) wacc[t >> 6] = local;
    __syncthreads();
    if (t == 0)
        out[0] = (wacc[0] + wacc[1] + wacc[2] + wacc[3])
                 * (1.0f / (BATCH * 0.69314718055994531f))
               + T * T * 0.01f;
}

extern "C" void kernel_launch(void* const* d_in, const int* in_sizes, int n_in,
                              void* d_out, int out_size, void* d_ws, size_t ws_size,
                              hipStream_t stream) {
    const int*   single_card = (const int*)d_in[0];
    const float* adj         = (const float*)d_in[1];
    const float* ce          = (const float*)d_in[2];
    const float* W1          = (const float*)d_in[3];
    const float* b1          = (const float*)d_in[4];
    const float* W2          = (const float*)d_in[5];
    const float* b2          = (const float*)d_in[6];
    const float* temp        = (const float*)d_in[7];

    char* ws = (char*)d_ws;
    unsigned short* Abf = (unsigned short*)(ws + A_OFF);
    unsigned short* Bbf = (unsigned short*)(ws + B_OFF);
    float* S            = (float*)(ws + S_OFF);

    prep_kernel<<<PREP_BBLOCKS + 128, 256, 0, stream>>>(single_card, ce, W1, b1, W2, b2,
                                                        Abf, Bbf, S);
    fused_kernel<<<dim3(GRIDX, GRIDY), 256, 0, stream>>>(Abf, Bbf, adj, temp, S);
    fin_kernel<<<1, 256, 0, stream>>>(S, temp, (float*)d_out);
}